// Round 6
// baseline (2686.408 us; speedup 1.0000x reference)
//
#include <hip/hip_runtime.h>

#define NBUS 131072
#define NGEN 32768
#define NALL (NBUS + NGEN)
#define NEBB 2097152
#define NEGB 65536
#define NEBG 65536
#define NEBUS (NEBB + NEGB)  // merged bus-dest CSR (bb + gb)
#define NGRP 8               // channel groups (8 ch x bf16 = 16 B per row-slice)

typedef float f32x2 __attribute__((ext_vector_type(2)));
typedef unsigned short u16;

__device__ inline f32x2 bf2x2(unsigned v) {  // unpack 2 bf16 (packed u32) -> 2 f32
  f32x2 r;
  r.x = __builtin_bit_cast(float, v << 16);
  r.y = __builtin_bit_cast(float, v & 0xFFFF0000u);
  return r;
}
__device__ inline u16 f2bf(float f) {  // round-to-nearest-even
  unsigned u = __builtin_bit_cast(unsigned, f);
  unsigned r = u + 0x7FFFu + ((u >> 16) & 1u);
  return (u16)(r >> 16);
}
__device__ inline unsigned pack2bf(float a, float b) {
  return (unsigned)f2bf(a) | ((unsigned)f2bf(b) << 16);
}

// ---------------- CSR build ----------------
__global__ void k_hist(const int* __restrict__ dst, int* __restrict__ counts, int nE) {
  int stride = gridDim.x * blockDim.x;
  for (int i = blockIdx.x * blockDim.x + threadIdx.x; i < nE; i += stride)
    atomicAdd(&counts[dst[i]], 1);
}

__global__ void k_scan1(const int* __restrict__ in, int* __restrict__ out,
                        int* __restrict__ bsums, int n) {
  __shared__ int sh[256];
  int t = threadIdx.x;
  int base = blockIdx.x * 1024 + t * 4;
  int v0 = (base + 0 < n) ? in[base + 0] : 0;
  int v1 = (base + 1 < n) ? in[base + 1] : 0;
  int v2 = (base + 2 < n) ? in[base + 2] : 0;
  int v3 = (base + 3 < n) ? in[base + 3] : 0;
  int t0 = v0, t1 = t0 + v1, t2 = t1 + v2, t3 = t2 + v3;
  sh[t] = t3;
  __syncthreads();
  for (int off = 1; off < 256; off <<= 1) {
    int x = (t >= off) ? sh[t - off] : 0;
    __syncthreads();
    sh[t] += x;
    __syncthreads();
  }
  int excl = (t > 0) ? sh[t - 1] : 0;
  if (base + 0 < n) out[base + 0] = excl;
  if (base + 1 < n) out[base + 1] = excl + t0;
  if (base + 2 < n) out[base + 2] = excl + t1;
  if (base + 3 < n) out[base + 3] = excl + t2;
  if (t == 255) bsums[blockIdx.x] = sh[255];
}

__global__ void k_scan2(int* __restrict__ bsums, int nb) {
  __shared__ int sh[256];
  int t = threadIdx.x;
  int v = (t < nb) ? bsums[t] : 0;
  sh[t] = v;
  __syncthreads();
  for (int off = 1; off < 256; off <<= 1) {
    int x = (t >= off) ? sh[t - off] : 0;
    __syncthreads();
    sh[t] += x;
    __syncthreads();
  }
  int excl = (t > 0) ? sh[t - 1] : 0;
  if (t < nb) bsums[t] = excl;
}

__global__ void k_scan3(int* __restrict__ off, int* __restrict__ cur,
                        const int* __restrict__ bsums, int n, int E) {
  int stride = gridDim.x * blockDim.x;
  for (int i = blockIdx.x * blockDim.x + threadIdx.x; i < n; i += stride) {
    int o = off[i] + bsums[i >> 10];
    off[i] = o;
    cur[i] = o;
  }
  if (blockIdx.x == 0 && threadIdx.x == 0) off[n] = E;
}

// srcOff encodes the source-feature section (gen rows live at NBUS+src)
__global__ void k_fill(const int* __restrict__ src, const int* __restrict__ dst,
                       int* __restrict__ cur, int* __restrict__ srt, int nE, int srcOff) {
  int stride = gridDim.x * blockDim.x;
  for (int i = blockIdx.x * blockDim.x + threadIdx.x; i < nE; i += stride) {
    int d = dst[i];
    int p = atomicAdd(&cur[d], 1);
    srt[p] = src[i] + srcOff;
  }
}

// ---------------- merged readin (bus+gen rows) + fused BN-stats ----------------
__global__ void __launch_bounds__(256) k_readin(const float* __restrict__ xbus,
                                                const float* __restrict__ xgen,
                                                const float* __restrict__ Wb,
                                                const float* __restrict__ bb_,
                                                const float* __restrict__ Wg,
                                                const float* __restrict__ bg_,
                                                float* __restrict__ y,
                                                float* __restrict__ stats) {
  __shared__ float WsB[2048];
  __shared__ float WsG[2048];
  __shared__ float shs[4][64];
  __shared__ float shs2[4][64];
  for (int i = threadIdx.x; i < 2048; i += 256) {
    WsB[i] = Wb[i];
    WsG[i] = Wg[i];
  }
  __syncthreads();
  int lane = threadIdx.x & 63;
  int wib = threadIdx.x >> 6;
  float bvB = bb_[lane], bvG = bg_[lane];
  int w = (blockIdx.x * blockDim.x + threadIdx.x) >> 6;
  int nw = (gridDim.x * blockDim.x) >> 6;
  float lsB = 0.f, ls2B = 0.f, lsG = 0.f, ls2G = 0.f;
  for (int g = w; g < NALL; g += nw) {
    bool isBus = g < NBUS;
    const float* xin = isBus ? xbus : xgen;
    int rl = isBus ? g : g - NBUS;
    const float* Ws = isBus ? WsB : WsG;
    float v = xin[(size_t)rl * 32 + (lane & 31)];
    float acc = isBus ? bvB : bvG;
#pragma unroll
    for (int i = 0; i < 32; i++) {
      float xi = __shfl(v, i, 64);
      acc = fmaf(xi, Ws[i * 64 + lane], acc);
    }
    y[(size_t)g * 64 + lane] = acc;
    if (isBus) {
      lsB += acc;
      ls2B = fmaf(acc, acc, ls2B);
    } else {
      lsG += acc;
      ls2G = fmaf(acc, acc, ls2G);
    }
  }
  shs[wib][lane] = lsB;
  shs2[wib][lane] = ls2B;
  __syncthreads();
  if (threadIdx.x < 64) {
    int c = threadIdx.x;
    atomicAdd(&stats[c], shs[0][c] + shs[1][c] + shs[2][c] + shs[3][c]);
  } else if (threadIdx.x < 128) {
    int c = threadIdx.x & 63;
    atomicAdd(&stats[64 + c], shs2[0][c] + shs2[1][c] + shs2[2][c] + shs2[3][c]);
  }
  __syncthreads();
  shs[wib][lane] = lsG;
  shs2[wib][lane] = ls2G;
  __syncthreads();
  if (threadIdx.x < 64) {
    int c = threadIdx.x;
    atomicAdd(&stats[128 + c], shs[0][c] + shs[1][c] + shs[2][c] + shs[3][c]);
  } else if (threadIdx.x < 128) {
    int c = threadIdx.x & 63;
    atomicAdd(&stats[192 + c], shs2[0][c] + shs2[1][c] + shs2[2][c] + shs2[3][c]);
  }
}

// ---------------- BN-finalize + normalize + lrelu + tap0; writes y in SLICED bf16 ----------------
// sliced layout: [g in 0..7][row in 0..NALL)[8 channels] bf16 (slab = 2.6 MB, L2-resident per XCD)
__global__ void __launch_bounds__(256) k_norm_tap0(float* __restrict__ x,
                                                   u16* __restrict__ c_sl,
                                                   const float* __restrict__ stats,
                                                   const float* __restrict__ gammaB,
                                                   const float* __restrict__ betaB,
                                                   const float* __restrict__ gammaG,
                                                   const float* __restrict__ betaG,
                                                   const float* __restrict__ Wb,
                                                   const float* __restrict__ bb_,
                                                   const float* __restrict__ Wg,
                                                   const float* __restrict__ bg_) {
  __shared__ float WsB[4096];
  __shared__ float WsG[4096];
  for (int i = threadIdx.x; i < 4096; i += 256) {
    WsB[i] = Wb[i];
    WsG[i] = Wg[i];
  }
  __syncthreads();
  int lane = threadIdx.x & 63;
  float mB = stats[lane] * (1.0f / NBUS);
  float m2B = stats[64 + lane] * (1.0f / NBUS);
  float rsB = rsqrtf(m2B - mB * mB + 1e-5f);
  float scaleB = gammaB[lane] * rsB;
  float shiftB = betaB[lane] - mB * scaleB;
  float mG = stats[128 + lane] * (1.0f / NGEN);
  float m2G = stats[192 + lane] * (1.0f / NGEN);
  float rsG = rsqrtf(m2G - mG * mG + 1e-5f);
  float scaleG = gammaG[lane] * rsG;
  float shiftG = betaG[lane] - mG * scaleG;
  float bvB = bb_[lane], bvG = bg_[lane];
  const int sg = lane >> 3;         // slab for this lane's channel pair
  const int scc = (lane & 7) >> 1;  // u32 slot within slab row
  unsigned* slu = (unsigned*)c_sl;
  int w = (blockIdx.x * blockDim.x + threadIdx.x) >> 6;
  int nw = (gridDim.x * blockDim.x) >> 6;
  for (int gr = w; gr < NALL; gr += nw) {
    bool isBus = gr < NBUS;
    float scale = isBus ? scaleB : scaleG;
    float shift = isBus ? shiftB : shiftG;
    const float* Ws = isBus ? WsB : WsG;
    size_t idx = (size_t)gr * 64 + lane;
    float xv = x[idx];
    float y = fmaf(xv, scale, shift);
    y = (y >= 0.f) ? y : 0.01f * y;
    float ypair = __shfl(y, lane ^ 1, 64);
    if ((lane & 1) == 0)  // even lane packs (even ch, odd ch) -> sliced slab
      slu[((size_t)sg * NALL + gr) * 4 + scc] = pack2bf(y, ypair);
    float acc = isBus ? bvB : bvG;
#pragma unroll
    for (int i = 0; i < 64; i++) {
      float yi = __shfl(y, i, 64);
      acc = fmaf(yi, Ws[i * 64 + lane], acc);
    }
    x[idx] = xv + acc;
  }
}

// ---------------- phase A: pure CSR gather from SLICED source (XCD-local L2) --------------
// group = blockIdx & 7 -> one 2.6 MB slab per XCD. 16 rows/wave x 4 lanes (2 ch each).
__global__ void __launch_bounds__(256) k_gather(const int* __restrict__ busOff,
                                                const int* __restrict__ busSrt,
                                                const int* __restrict__ bgOff,
                                                const int* __restrict__ bgSrt,
                                                const u16* __restrict__ src_sl,
                                                u16* __restrict__ dst_sl,
                                                u16* __restrict__ dst_rm) {
  const int lane = threadIdx.x & 63;
  const int wv = threadIdx.x >> 6;  // wave in block (0..3)
  const int grp = lane >> 2;        // row slot (0..15)
  const int cc = lane & 3;          // u32 slot (2 channels)
  const int g = blockIdx.x & 7;     // channel group -> XCD
  const int blk = blockIdx.x >> 3;
  const int nblk = gridDim.x >> 3;
  const unsigned* src32 = (const unsigned*)src_sl + (size_t)g * NALL * 4;
  unsigned* dsl = dst_sl ? (unsigned*)dst_sl + (size_t)g * NALL * 4 : (unsigned*)0;
  unsigned* drm = (unsigned*)dst_rm;
  for (int base = blk * 64; base < NALL; base += nblk * 64) {
    int row = base + wv * 16 + grp;  // NALL % 64 == 0 -> always in range
    int beg, end;
    const int* srt;
    if (row < NBUS) {
      beg = busOff[row];
      end = busOff[row + 1];
      srt = busSrt;
    } else {
      int rr = row - NBUS;
      beg = bgOff[rr];
      end = bgOff[rr + 1];
      srt = bgSrt;
    }
    f32x2 a0 = {0.f, 0.f}, a1 = {0.f, 0.f}, a2 = {0.f, 0.f}, a3 = {0.f, 0.f};
    int e = beg;
    for (; e + 8 <= end; e += 8) {
      int s0 = srt[e + 0], s1 = srt[e + 1], s2 = srt[e + 2], s3 = srt[e + 3];
      int s4 = srt[e + 4], s5 = srt[e + 5], s6 = srt[e + 6], s7 = srt[e + 7];
      unsigned v0 = src32[(size_t)s0 * 4 + cc];
      unsigned v1 = src32[(size_t)s1 * 4 + cc];
      unsigned v2 = src32[(size_t)s2 * 4 + cc];
      unsigned v3 = src32[(size_t)s3 * 4 + cc];
      unsigned v4 = src32[(size_t)s4 * 4 + cc];
      unsigned v5 = src32[(size_t)s5 * 4 + cc];
      unsigned v6 = src32[(size_t)s6 * 4 + cc];
      unsigned v7 = src32[(size_t)s7 * 4 + cc];
      a0 += bf2x2(v0); a1 += bf2x2(v1); a2 += bf2x2(v2); a3 += bf2x2(v3);
      a0 += bf2x2(v4); a1 += bf2x2(v5); a2 += bf2x2(v6); a3 += bf2x2(v7);
    }
    for (; e + 4 <= end; e += 4) {
      int s0 = srt[e + 0], s1 = srt[e + 1], s2 = srt[e + 2], s3 = srt[e + 3];
      unsigned v0 = src32[(size_t)s0 * 4 + cc];
      unsigned v1 = src32[(size_t)s1 * 4 + cc];
      unsigned v2 = src32[(size_t)s2 * 4 + cc];
      unsigned v3 = src32[(size_t)s3 * 4 + cc];
      a0 += bf2x2(v0); a1 += bf2x2(v1); a2 += bf2x2(v2); a3 += bf2x2(v3);
    }
    for (; e < end; e++)
      a0 += bf2x2(src32[(size_t)srt[e] * 4 + cc]);
    f32x2 acc = (a0 + a1) + (a2 + a3);
    unsigned pk = pack2bf(acc.x, acc.y);
    if (dsl) dsl[(size_t)row * 4 + cc] = pk;          // next gather source (sliced)
    drm[(size_t)row * 32 + g * 4 + cc] = pk;          // row-major for phase-B GEMM
  }
}

// ---------------- phase B: tap GEMM x += acc@W + b (+ optional BN-stats) ----------------
__global__ void __launch_bounds__(256) k_tap(const u16* __restrict__ rm,
                                             float* __restrict__ x,
                                             const float* __restrict__ Wb,
                                             const float* __restrict__ bb_,
                                             const float* __restrict__ Wg,
                                             const float* __restrict__ bg_,
                                             float* __restrict__ stats) {
  __shared__ float WsB[4096];
  __shared__ float WsG[4096];
  __shared__ f32x2 shS[256];
  __shared__ f32x2 shS2[256];
  for (int i = threadIdx.x; i < 4096; i += 256) {
    WsB[i] = Wb[i];
    WsG[i] = Wg[i];
  }
  __syncthreads();
  const int lane = threadIdx.x & 63;
  const int half = lane >> 5;
  const int sub = lane & 31;
  const int c0 = sub * 2;
  const int h32 = half * 32;
  const f32x2 bvB = *(const f32x2*)&bb_[c0];
  const f32x2 bvG = *(const f32x2*)&bg_[c0];
  const unsigned* rm32 = (const unsigned*)rm;
  f32x2 lsB = {0.f, 0.f}, ls2B = {0.f, 0.f}, lsG = {0.f, 0.f}, ls2G = {0.f, 0.f};
  int w = (blockIdx.x * blockDim.x + threadIdx.x) >> 6;
  int nw = (gridDim.x * blockDim.x) >> 6;
  const int PB = NBUS / 2, PT = NALL / 2;
  for (int pr = w; pr < PT; pr += nw) {
    bool isBus = pr < PB;
    int g = pr * 2 + half;
    f32x2 acc = bf2x2(rm32[(size_t)g * 32 + sub]);
    const float* Ws = isBus ? WsB : WsG;
    f32x2 bv = isBus ? bvB : bvG;
    float zx = bv.x, zy = bv.y;
#pragma unroll
    for (int t = 0; t < 32; ++t) {
      float nx = __shfl(acc.x, h32 + t, 64);
      float ny = __shfl(acc.y, h32 + t, 64);
      f32x2 w0 = *(const f32x2*)&Ws[(2 * t) * 64 + c0];
      f32x2 w1 = *(const f32x2*)&Ws[(2 * t + 1) * 64 + c0];
      zx = fmaf(nx, w0.x, zx);
      zy = fmaf(nx, w0.y, zy);
      zx = fmaf(ny, w1.x, zx);
      zy = fmaf(ny, w1.y, zy);
    }
    size_t idx = (size_t)g * 64 + c0;
    f32x2 xv = *(const f32x2*)&x[idx];
    f32x2 xo = {xv.x + zx, xv.y + zy};
    *(f32x2*)&x[idx] = xo;
    if (isBus) {
      lsB += xo;
      ls2B.x = fmaf(xo.x, xo.x, ls2B.x);
      ls2B.y = fmaf(xo.y, xo.y, ls2B.y);
    } else {
      lsG += xo;
      ls2G.x = fmaf(xo.x, xo.x, ls2G.x);
      ls2G.y = fmaf(xo.y, xo.y, ls2G.y);
    }
  }
  if (stats) {
    shS[threadIdx.x] = lsB;
    shS2[threadIdx.x] = ls2B;
    __syncthreads();
    if (threadIdx.x < 32) {
      f32x2 s = shS[threadIdx.x], s2 = shS2[threadIdx.x];
      for (int t = threadIdx.x + 32; t < 256; t += 32) {
        s += shS[t];
        s2 += shS2[t];
      }
      atomicAdd(&stats[2 * threadIdx.x], s.x);
      atomicAdd(&stats[2 * threadIdx.x + 1], s.y);
      atomicAdd(&stats[64 + 2 * threadIdx.x], s2.x);
      atomicAdd(&stats[64 + 2 * threadIdx.x + 1], s2.y);
    }
    __syncthreads();
    shS[threadIdx.x] = lsG;
    shS2[threadIdx.x] = ls2G;
    __syncthreads();
    if (threadIdx.x < 32) {
      f32x2 s = shS[threadIdx.x], s2 = shS2[threadIdx.x];
      for (int t = threadIdx.x + 32; t < 256; t += 32) {
        s += shS[t];
        s2 += shS2[t];
      }
      atomicAdd(&stats[128 + 2 * threadIdx.x], s.x);
      atomicAdd(&stats[128 + 2 * threadIdx.x + 1], s.y);
      atomicAdd(&stats[192 + 2 * threadIdx.x], s2.x);
      atomicAdd(&stats[192 + 2 * threadIdx.x + 1], s2.y);
    }
  }
}

// ---------------- merged readout ----------------
__global__ void __launch_bounds__(256) k_readout(const float* __restrict__ x,
                                                 const float* __restrict__ Wb,
                                                 const float* __restrict__ bb_,
                                                 const float* __restrict__ Wg,
                                                 const float* __restrict__ bg_,
                                                 float* __restrict__ out) {
  __shared__ float WsB[2048];
  __shared__ float WsG[2048];
  __shared__ float bsB[32];
  __shared__ float bsG[32];
  for (int i = threadIdx.x; i < 2048; i += 256) {
    WsB[i] = Wb[i];
    WsG[i] = Wg[i];
  }
  if (threadIdx.x < 32) {
    bsB[threadIdx.x] = bb_[threadIdx.x];
    bsG[threadIdx.x] = bg_[threadIdx.x];
  }
  __syncthreads();
  int lane = threadIdx.x & 63;
  int ch = lane & 31;
  int w = (blockIdx.x * blockDim.x + threadIdx.x) >> 6;
  int nw = (gridDim.x * blockDim.x) >> 6;
  for (int g = w; g < NALL; g += nw) {
    bool isBus = g < NBUS;
    const float* Ws = isBus ? WsB : WsG;
    float v = x[(size_t)g * 64 + lane];
    float acc = isBus ? bsB[ch] : bsG[ch];
#pragma unroll
    for (int i = 0; i < 64; i++) {
      float xi = __shfl(v, i, 64);
      acc = fmaf(xi, Ws[i * 32 + ch], acc);
    }
    if (lane < 32) out[(size_t)g * 32 + ch] = acc;
  }
}

extern "C" void kernel_launch(void* const* d_in, const int* in_sizes, int n_in,
                              void* d_out, int out_size, void* d_ws, size_t ws_size,
                              hipStream_t stream) {
  const float* x_bus = (const float*)d_in[0];
  const float* x_gen = (const float*)d_in[1];
  const float* riWb = (const float*)d_in[2];
  const float* ribb = (const float*)d_in[3];
  const float* riWg = (const float*)d_in[4];
  const float* ribg = (const float*)d_in[5];
  const float* bng_b = (const float*)d_in[6];
  const float* bnb_b = (const float*)d_in[7];
  const float* bng_g = (const float*)d_in[8];
  const float* bnb_g = (const float*)d_in[9];
  const float* tWb = (const float*)d_in[10];
  const float* tbb = (const float*)d_in[11];
  const float* tWg = (const float*)d_in[12];
  const float* tbg = (const float*)d_in[13];
  const float* roWb = (const float*)d_in[14];
  const float* robb = (const float*)d_in[15];
  const float* roWg = (const float*)d_in[16];
  const float* robg = (const float*)d_in[17];
  const int* ebb = (const int*)d_in[18];
  const int* gb_src = (const int*)d_in[19];
  const int* gb_dst = (const int*)d_in[20];
  const int* bg_src = (const int*)d_in[21];
  const int* bg_dst = (const int*)d_in[22];
  const int* bb_src = ebb;
  const int* bb_dst = ebb + NEBB;

  // ---- workspace layout (256B aligned segments) ----
  char* p = (char*)d_ws;
  auto take = [&](size_t bytes) -> void* {
    void* r = (void*)p;
    p += (bytes + 255) & ~(size_t)255;
    return r;
  };
  float* x = (float*)take((size_t)NALL * 64 * 4);   // bus rows [0,NBUS), gen rows after
  u16* sl0 = (u16*)take((size_t)NALL * 64 * 2);     // sliced bf16 shift state (ping)
  u16* sl1 = (u16*)take((size_t)NALL * 64 * 2);     // sliced bf16 shift state (pong)
  u16* rm = (u16*)take((size_t)NALL * 64 * 2);      // row-major bf16 acc (per tap)
  int* bus_off = (int*)take((size_t)(NBUS + 1) * 4);
  int* bus_cur = (int*)take((size_t)NBUS * 4);
  int* bus_srt = (int*)take((size_t)NEBUS * 4);
  int* bg_off = (int*)take((size_t)(NGEN + 1) * 4);
  int* bg_cur = (int*)take((size_t)NGEN * 4);
  int* bg_srt = (int*)take((size_t)NEBG * 4);
  int* bsums = (int*)take(256 * 4);
  float* stats0 = (float*)take(256 * 4);  // [bus s, bus s2, gen s, gen s2]
  float* stats1 = (float*)take(256 * 4);
  if ((size_t)(p - (char*)d_ws) > ws_size) return;  // ws too small -> visible validation failure

  // ---- CSR build (merged bus CSR: bb edges + gb edges with src+NBUS) ----
  hipMemsetAsync(bus_cur, 0, (size_t)NBUS * 4, stream);
  hipMemsetAsync(bg_cur, 0, (size_t)NGEN * 4, stream);
  hipMemsetAsync(stats0, 0, 512 * 4, stream);  // stats0 + stats1 (contiguous)

  k_hist<<<2048, 256, 0, stream>>>(bb_dst, bus_cur, NEBB);
  k_hist<<<256, 256, 0, stream>>>(gb_dst, bus_cur, NEGB);
  k_hist<<<256, 256, 0, stream>>>(bg_dst, bg_cur, NEBG);

  k_scan1<<<128, 256, 0, stream>>>(bus_cur, bus_off, bsums, NBUS);
  k_scan2<<<1, 256, 0, stream>>>(bsums, 128);
  k_scan3<<<512, 256, 0, stream>>>(bus_off, bus_cur, bsums, NBUS, NEBUS);

  k_scan1<<<32, 256, 0, stream>>>(bg_cur, bg_off, bsums, NGEN);
  k_scan2<<<1, 256, 0, stream>>>(bsums, 32);
  k_scan3<<<128, 256, 0, stream>>>(bg_off, bg_cur, bsums, NGEN, NEBG);

  k_fill<<<2048, 256, 0, stream>>>(bb_src, bb_dst, bus_cur, bus_srt, NEBB, 0);
  k_fill<<<256, 256, 0, stream>>>(gb_src, gb_dst, bus_cur, bus_srt, NEGB, NBUS);
  k_fill<<<256, 256, 0, stream>>>(bg_src, bg_dst, bg_cur, bg_srt, NEBG, 0);

  // ---- readin (+ layer-0 BN stats) ----
  k_readin<<<5120, 256, 0, stream>>>(x_bus, x_gen, riWb, ribb, riWg, ribg, x, stats0);

  // ---- residual blocks ----
  u16* cur = sl0;
  u16* nxt = sl1;
  for (int l = 0; l < 2; l++) {
    float* statsL = (l == 0) ? stats0 : stats1;
    k_norm_tap0<<<5120, 256, 0, stream>>>(x, cur, statsL,
                                          bng_b + l * 64, bnb_b + l * 64,
                                          bng_g + l * 64, bnb_g + l * 64,
                                          tWb + (size_t)(l * 5) * 4096,
                                          tbb + (size_t)(l * 5) * 64,
                                          tWg + (size_t)(l * 5) * 4096,
                                          tbg + (size_t)(l * 5) * 64);
    for (int k = 1; k < 5; k++) {
      u16* dsl = (k < 4) ? nxt : (u16*)nullptr;  // last tap's sliced output unused
      k_gather<<<2048, 256, 0, stream>>>(bus_off, bus_srt, bg_off, bg_srt, cur, dsl, rm);
      float* so = (l == 0 && k == 4) ? stats1 : (float*)nullptr;
      k_tap<<<4096, 256, 0, stream>>>(rm, x,
                                      tWb + (size_t)(l * 5 + k) * 4096,
                                      tbb + (size_t)(l * 5 + k) * 64,
                                      tWg + (size_t)(l * 5 + k) * 4096,
                                      tbg + (size_t)(l * 5 + k) * 64, so);
      u16* t = cur; cur = nxt; nxt = t;
    }
  }

  // ---- readout ----
  k_readout<<<5120, 256, 0, stream>>>(x, roWb, robb, roWg, robg, (float*)d_out);
}